// Round 1
// baseline (128.023 us; speedup 1.0000x reference)
//
#include <hip/hip_runtime.h>

#define BATCH 262144
#define HID 64
#define NSTEP 50

// One thread per batch element. h-outer / t-inner: per-h weights are
// wave-uniform scalar loads; acc[t] accumulates layer-2 current in exact
// h-sequential fma order (matches BLAS sgemm single-accumulator microkernel).
// All recurrence arithmetic uses explicit _rn intrinsics -> no contraction,
// matching numpy's separate mul/add/sub rounding.
__global__ __launch_bounds__(256) void snn_fused(
    const float* __restrict__ x,
    const float* __restrict__ W1,
    const float* __restrict__ b1,
    const float* __restrict__ W2,
    const float* __restrict__ b2,
    float* __restrict__ out)
{
    const int b = blockIdx.x * 256 + threadIdx.x;
    const float2 xv = reinterpret_cast<const float2*>(x)[b];

    float acc0[NSTEP], acc1[NSTEP];
#pragma unroll
    for (int t = 0; t < NSTEP; ++t) { acc0[t] = 0.0f; acc1[t] = 0.0f; }

#pragma unroll 2
    for (int h = 0; h < HID; ++h) {
        const float w10 = W1[2 * h + 0];
        const float w11 = W1[2 * h + 1];
        const float w20 = W2[h];          // W2[0][h], W2 is [2][64] row-major
        const float w21 = W2[HID + h];    // W2[1][h]
        // cur1 = x @ W1.T (+ b1 as separate rounded add), sgemm-style fma chain
        float c = __fmul_rn(xv.x, w10);
        c = __builtin_fmaf(xv.y, w11, c);
        const float cur = __fadd_rn(c, b1[h]);

        float m = 0.0f;    // mem1_h
        float spk = 0.0f;  // spk1_h(t-1) == reset1(t); H(0-1)=0 initially
#pragma unroll
        for (int t = 0; t < NSTEP; ++t) {
            // mem1 = (BETA*mem1 + cur1) - reset1*THRESH, exact op order
            m = __fsub_rn(__fadd_rn(__fmul_rn(0.95f, m), cur), spk);
            spk = (m > 1.0f) ? 1.0f : 0.0f;  // H(mem1 - 1)
            // cur2 partial sums, h-sequential fma accumulation order
            acc0[t] = __builtin_fmaf(spk, w20, acc0[t]);
            acc1[t] = __builtin_fmaf(spk, w21, acc1[t]);
        }
    }

    // Layer 2: 50 sequential LIF steps on 2 output neurons + coalesced writes.
    const float bb0 = b2[0], bb1 = b2[1];
    float m0 = 0.0f, m1 = 0.0f, s0 = 0.0f, s1 = 0.0f;
    float2* outspk = reinterpret_cast<float2*>(out) + b;                       // [t][b][2]
    float2* outmem = reinterpret_cast<float2*>(out) + (size_t)NSTEP * BATCH + b;
#pragma unroll
    for (int t = 0; t < NSTEP; ++t) {
        const float c0 = __fadd_rn(acc0[t], bb0);  // + b2 as separate add
        const float c1 = __fadd_rn(acc1[t], bb1);
        m0 = __fsub_rn(__fadd_rn(__fmul_rn(0.95f, m0), c0), s0);
        m1 = __fsub_rn(__fadd_rn(__fmul_rn(0.95f, m1), c1), s1);
        s0 = (m0 > 1.0f) ? 1.0f : 0.0f;
        s1 = (m1 > 1.0f) ? 1.0f : 0.0f;
        outspk[(size_t)t * BATCH] = make_float2(s0, s1);
        outmem[(size_t)t * BATCH] = make_float2(m0, m1);
    }
}

extern "C" void kernel_launch(void* const* d_in, const int* in_sizes, int n_in,
                              void* d_out, int out_size, void* d_ws, size_t ws_size,
                              hipStream_t stream)
{
    const float* x  = (const float*)d_in[0];
    const float* W1 = (const float*)d_in[1];
    const float* b1 = (const float*)d_in[2];
    const float* W2 = (const float*)d_in[3];
    const float* b2 = (const float*)d_in[4];
    float* out = (float*)d_out;
    snn_fused<<<BATCH / 256, 256, 0, stream>>>(x, W1, b1, W2, b2, out);
}